// Round 1
// baseline (190.741 us; speedup 1.0000x reference)
//
#include <hip/hip_runtime.h>

// ---- constants -------------------------------------------------------------
// B=4, S=1024, K_ENC=512, H=1024, NH=16, HD=64
#define BATCH 4
#define SEQ   1024
#define KENC  512
#define HDIM  1024
#define NHEAD 16
#define HD    64

typedef __attribute__((ext_vector_type(8))) short bf16x8;
typedef __attribute__((ext_vector_type(4))) float f32x4;
typedef __attribute__((ext_vector_type(4))) float f4v;
typedef __attribute__((ext_vector_type(4))) short s4v;

__device__ __forceinline__ short f2bf(float f) {
  unsigned u = __float_as_uint(f);
  u += 0x7fffu + ((u >> 16) & 1u);   // RNE
  return (short)(u >> 16);
}

__device__ __forceinline__ void gload_lds16(const void* g, void* l) {
  __builtin_amdgcn_global_load_lds(
      (const __attribute__((address_space(1))) void*)g,
      (__attribute__((address_space(3))) void*)l, 16, 0, 0);
}

// ---- kernel 1: f32 -> bf16 cast (vectorized) -------------------------------
__global__ __launch_bounds__(256) void cast_bf16(const float* __restrict__ src,
                                                 short* __restrict__ dst, int n4) {
  int i = blockIdx.x * 256 + threadIdx.x;
  if (i >= n4) return;
  f4v v = ((const f4v*)src)[i];
  s4v o;
#pragma unroll
  for (int j = 0; j < 4; ++j) o[j] = f2bf(v[j]);
  ((s4v*)dst)[i] = o;
}

// ---- kernel 2: weight cast + transpose: Wt[n][k] = W[k][n] -----------------
struct WtArgs { const float* W[6]; };

__global__ __launch_bounds__(256) void wt_cast(WtArgs a, short* __restrict__ wt) {
  int j = blockIdx.z;
  const float* W = a.W[j];
  short* dst = wt + (size_t)j * (HDIM * HDIM);
  int cb = blockIdx.x * 32, rb = blockIdx.y * 32;
  __shared__ float t[32][33];
  int tx = threadIdx.x & 31, ty = threadIdx.x >> 5;
#pragma unroll
  for (int rr = 0; rr < 4; ++rr)
    t[ty + rr * 8][tx] = W[(size_t)(rb + ty + rr * 8) * HDIM + cb + tx];
  __syncthreads();
#pragma unroll
  for (int rr = 0; rr < 4; ++rr)
    dst[(size_t)(cb + ty + rr * 8) * HDIM + rb + tx] = f2bf(t[tx][ty + rr * 8]);
}

// ---- kernel 3: batched projection GEMM (128x128 tile, BK=32) ---------------
// C = X[M,1024] @ Wt^T (+bias). Outputs bf16 either [B,NH,T,HD] (std) or
// [B,NH,HD,T] (transposed, for V so PV B-fragments are contiguous along k).
struct ProjArgs {
  const short* X[6];
  const short* Wt[6];
  const float* bias[6];
  short* out[6];
  int M[6];
  int tshift[6];  // log2(tokens): 10 or 9
  int mode[6];    // 0 std, 1 transposed
};

__global__ __launch_bounds__(256) void proj_gemm(ProjArgs a) {
  int job = blockIdx.z;
  int M = a.M[job];
  int by = blockIdx.y;
  if (by * 128 >= M) return;
  int bx = blockIdx.x;
  const short* X = a.X[job];
  const short* W = a.Wt[job];

  __shared__ short As[128 * 32];
  __shared__ short Bs[128 * 32];

  int tid = threadIdx.x, lane = tid & 63, wave = tid >> 6;
  int wr = wave >> 1, wc = wave & 1;
  int l15 = lane & 15, g4 = lane >> 4;

  f32x4 acc[4][4];
#pragma unroll
  for (int m = 0; m < 4; ++m)
#pragma unroll
    for (int n = 0; n < 4; ++n)
#pragma unroll
      for (int r = 0; r < 4; ++r) acc[m][n][r] = 0.0f;

  int arow = by * 128, brow = bx * 128;
  // staging: chunk c = wave*2+cc covers 16 rows; lane -> row 16c+(l>>2),
  // 16B-group (l&3), source group pre-swizzled so reads are ~conflict-free.
  const int crow = lane >> 2;
  const int sgrp = (lane & 3) ^ ((lane >> 2) & 3) ^ (lane >> 4);  // source 16B group
  // read-side swizzle for a row r, k-group G: grp = G ^ (r&3) ^ ((r>>2)&3)
  const int rsw = (lane & 3) ^ ((l15) >> 2);  // (row&3)^((row>>2)&3) for row=..+l15

  for (int k0 = 0; k0 < HDIM; k0 += 32) {
#pragma unroll
    for (int cc = 0; cc < 2; ++cc) {
      int c = wave * 2 + cc;
      gload_lds16(X + (size_t)(arow + c * 16 + crow) * HDIM + k0 + sgrp * 8,
                  (char*)As + c * 1024);
      gload_lds16(W + (size_t)(brow + c * 16 + crow) * HDIM + k0 + sgrp * 8,
                  (char*)Bs + c * 1024);
    }
    __syncthreads();
    bf16x8 af[4], bfr[4];
#pragma unroll
    for (int m = 0; m < 4; ++m)
      af[m] = *(const bf16x8*)((const char*)As + (wr * 64 + m * 16 + l15) * 64 +
                               ((g4 ^ rsw) << 4));
#pragma unroll
    for (int n = 0; n < 4; ++n)
      bfr[n] = *(const bf16x8*)((const char*)Bs + (wc * 64 + n * 16 + l15) * 64 +
                                ((g4 ^ rsw) << 4));
#pragma unroll
    for (int m = 0; m < 4; ++m)
#pragma unroll
      for (int n = 0; n < 4; ++n)
        acc[m][n] = __builtin_amdgcn_mfma_f32_16x16x32_bf16(af[m], bfr[n],
                                                            acc[m][n], 0, 0, 0);
    __syncthreads();
  }

  const float* bias = a.bias[job];
  short* out = a.out[job];
  int tshift = a.tshift[job], tmask = (1 << tshift) - 1, mode = a.mode[job];
#pragma unroll
  for (int m = 0; m < 4; ++m) {
    int rowb = arow + wr * 64 + m * 16 + (g4 << 2);
#pragma unroll
    for (int n = 0; n < 4; ++n) {
      int col = brow + wc * 64 + n * 16 + l15;
      float bv = bias[col];
      int head = col >> 6, d = col & 63;
#pragma unroll
      for (int r = 0; r < 4; ++r) {
        int row = rowb + r;
        int bb = row >> tshift, t = row & tmask;
        float val = acc[m][n][r] + bv;
        size_t idx;
        if (mode == 0)
          idx = ((((size_t)bb * NHEAD + head) << tshift) + t) * 64 + d;
        else
          idx = ((((size_t)bb * NHEAD + head) * 64 + d) << tshift) + t;
        out[idx] = f2bf(val);
      }
    }
  }
}

// ---- kernel 4: fused dual-branch flash attention ---------------------------
// 4 waves/block, wave = 16 q rows, KVBLK = 64.  K tile [64][64] and Vt tile
// [64 d][64 t] staged via global_load_lds with pre-swizzled source (XOR row&7
// on 16B groups) so frag ds_read_b128 are 2-way (free).  P goes through
// per-wave swizzled LDS to re-layout D->A fragments.
__device__ __forceinline__ void run_branch(
    const short* __restrict__ kp, const short* __restrict__ vp,
    const float* __restrict__ mp, int nt, int T, const bf16x8* qf,
    short* Ks, short* Vs, short* Pw, int lane, int wave, f32x4* outctx) {
  const int l7 = lane & 7, l15 = lane & 15, g4 = lane >> 4;
  const int srow = lane >> 3;                 // row within 8-row chunk
  const int scol = ((lane & 7) ^ srow) * 8;   // pre-swizzled source elem offset

  f32x4 ctx[4], mr, lr;
#pragma unroll
  for (int i = 0; i < 4; ++i) {
#pragma unroll
    for (int r = 0; r < 4; ++r) ctx[i][r] = 0.0f;
    mr[i] = -1e30f;
    lr[i] = 0.0f;
  }

  for (int kt = 0; kt < nt; ++kt) {
#pragma unroll
    for (int cc = 0; cc < 2; ++cc) {
      int c = wave * 2 + cc;
      int row = c * 8 + srow;
      gload_lds16(kp + (size_t)(kt * 64 + row) * 64 + scol, (char*)Ks + c * 1024);
      gload_lds16(vp + (size_t)row * T + kt * 64 + scol, (char*)Vs + c * 1024);
    }
    __syncthreads();

    f32x4 sc[4];
#pragma unroll
    for (int i = 0; i < 4; ++i)
#pragma unroll
      for (int r = 0; r < 4; ++r) sc[i][r] = 0.0f;

#pragma unroll
    for (int dk = 0; dk < 2; ++dk)
#pragma unroll
      for (int t2 = 0; t2 < 4; ++t2) {
        bf16x8 kf = *(const bf16x8*)((const char*)Ks + (t2 * 16 + l15) * 128 +
                                     (((dk * 4 + g4) ^ l7) << 4));
        sc[t2] = __builtin_amdgcn_mfma_f32_16x16x32_bf16(qf[dk], kf, sc[t2], 0, 0, 0);
      }

    // scale + mask
#pragma unroll
    for (int t2 = 0; t2 < 4; ++t2) {
      float mk = mp[kt * 64 + t2 * 16 + l15];
#pragma unroll
      for (int r = 0; r < 4; ++r) sc[t2][r] = sc[t2][r] * 0.125f + mk;
    }

    // online softmax (rows live in regs, cols across 16-lane group)
    f32x4 rm;
#pragma unroll
    for (int r = 0; r < 4; ++r)
      rm[r] = fmaxf(fmaxf(sc[0][r], sc[1][r]), fmaxf(sc[2][r], sc[3][r]));
#pragma unroll
    for (int off = 1; off < 16; off <<= 1)
#pragma unroll
      for (int r = 0; r < 4; ++r) rm[r] = fmaxf(rm[r], __shfl_xor(rm[r], off));

    f32x4 mnew, scl, rs, p[4];
#pragma unroll
    for (int r = 0; r < 4; ++r) {
      mnew[r] = fmaxf(mr[r], rm[r]);
      scl[r] = __expf(mr[r] - mnew[r]);
      rs[r] = 0.0f;
    }
#pragma unroll
    for (int t2 = 0; t2 < 4; ++t2)
#pragma unroll
      for (int r = 0; r < 4; ++r) {
        p[t2][r] = __expf(sc[t2][r] - mnew[r]);
        rs[r] += p[t2][r];
      }
#pragma unroll
    for (int off = 1; off < 16; off <<= 1)
#pragma unroll
      for (int r = 0; r < 4; ++r) rs[r] += __shfl_xor(rs[r], off);
#pragma unroll
    for (int r = 0; r < 4; ++r) {
      lr[r] = lr[r] * scl[r] + rs[r];
      mr[r] = mnew[r];
    }
#pragma unroll
    for (int dt = 0; dt < 4; ++dt)
#pragma unroll
      for (int r = 0; r < 4; ++r) ctx[dt][r] *= scl[r];

    // P -> per-wave LDS (swizzled), then read A-fragments
#pragma unroll
    for (int t2 = 0; t2 < 4; ++t2) {
      int gg = t2 * 2 + (l15 >> 3);
#pragma unroll
      for (int r4 = 0; r4 < 4; ++r4) {
        int r = g4 * 4 + r4;
        *(short*)((char*)Pw + r * 128 + (((gg ^ (r & 7)) << 4) | (l7 * 2))) =
            f2bf(p[t2][r4]);
      }
    }
#pragma unroll
    for (int kc = 0; kc < 2; ++kc) {
      bf16x8 pf = *(const bf16x8*)((const char*)Pw + l15 * 128 +
                                   (((kc * 4 + g4) ^ l7) << 4));
#pragma unroll
      for (int dt = 0; dt < 4; ++dt) {
        bf16x8 vf = *(const bf16x8*)((const char*)Vs + (dt * 16 + l15) * 128 +
                                     (((kc * 4 + g4) ^ l7) << 4));
        ctx[dt] = __builtin_amdgcn_mfma_f32_16x16x32_bf16(pf, vf, ctx[dt], 0, 0, 0);
      }
    }
    __syncthreads();
  }
#pragma unroll
  for (int dt = 0; dt < 4; ++dt)
#pragma unroll
    for (int r = 0; r < 4; ++r) outctx[dt][r] = ctx[dt][r] / lr[r];
}

__global__ __launch_bounds__(256) void attn_kernel(
    const short* __restrict__ qall, const short* __restrict__ kall,
    const short* __restrict__ vTall, const short* __restrict__ kqall,
    const short* __restrict__ kkall, const short* __restrict__ kvTall,
    const float* __restrict__ amask, const float* __restrict__ emask,
    float* __restrict__ out) {
  __shared__ short Ks[64 * 64];
  __shared__ short Vs[64 * 64];
  __shared__ short Ps[4 * 16 * 64];

  int lid = blockIdx.x;
  int id = ((lid & 7) << 7) | (lid >> 3);   // XCD-chunked swizzle (1024 = 8*128)
  int bh = id >> 4, qb = id & 15;
  int b = bh >> 4, h = bh & 15;
  int lane = threadIdx.x & 63, wave = threadIdx.x >> 6;
  int l15 = lane & 15, g4 = lane >> 4;
  int qbase = qb * 64;

  const short* qp = qall + ((size_t)bh * SEQ + qbase + wave * 16) * 64;
  const short* kqp = kqall + ((size_t)bh * SEQ + qbase + wave * 16) * 64;
  bf16x8 qf[2], kqf[2];
#pragma unroll
  for (int dk = 0; dk < 2; ++dk) {
    qf[dk] = *(const bf16x8*)(qp + l15 * 64 + dk * 32 + g4 * 8);
    kqf[dk] = *(const bf16x8*)(kqp + l15 * 64 + dk * 32 + g4 * 8);
  }

  f32x4 c1[4], c2[4];
  run_branch(kall + (size_t)bh * SEQ * 64, vTall + (size_t)bh * 64 * SEQ,
             amask + b * SEQ, SEQ / 64, SEQ, qf, Ks, Vs, Ps + wave * 1024, lane,
             wave, c1);
  run_branch(kkall + (size_t)bh * KENC * 64, kvTall + (size_t)bh * 64 * KENC,
             emask + b * KENC, KENC / 64, KENC, kqf, Ks, Vs, Ps + wave * 1024,
             lane, wave, c2);

#pragma unroll
  for (int dt = 0; dt < 4; ++dt)
#pragma unroll
    for (int r = 0; r < 4; ++r) {
      int s = qbase + wave * 16 + g4 * 4 + r;
      int d = dt * 16 + l15;
      out[((size_t)b * SEQ + s) * HDIM + h * 64 + d] = 0.5f * (c1[dt][r] + c2[dt][r]);
    }
}

// ---- host launcher ---------------------------------------------------------
extern "C" void kernel_launch(void* const* d_in, const int* in_sizes, int n_in,
                              void* d_out, int out_size, void* d_ws, size_t ws_size,
                              hipStream_t stream) {
  const float* hid = (const float*)d_in[0];
  const float* enc = (const float*)d_in[1];
  const float* amask = (const float*)d_in[2];
  const float* emask = (const float*)d_in[3];

  char* ws = (char*)d_ws;
  short* hbf = (short*)(ws);                        // 8 MB  [B*S,H] bf16
  short* ebf = (short*)(ws + (8u << 20));           // 4 MB  [B*K,H]
  short* wt = (short*)(ws + (12u << 20));           // 12 MB 6x [n][k]
  short* qo = (short*)(ws + (24u << 20));           // 8 MB  [B,NH,S,HD]
  short* ko = (short*)(ws + (32u << 20));           // 8 MB
  short* vT = (short*)(ws + (40u << 20));           // 8 MB  [B,NH,HD,S]
  short* kqo = (short*)(ws + (48u << 20));          // 8 MB
  short* kko = (short*)(ws + (56u << 20));          // 4 MB  [B,NH,K,HD]
  short* kvT = (short*)(ws + (60u << 20));          // 4 MB  [B,NH,HD,K]

  cast_bf16<<<4096, 256, 0, stream>>>(hid, hbf, (BATCH * SEQ * HDIM) / 4);
  cast_bf16<<<2048, 256, 0, stream>>>(enc, ebf, (BATCH * KENC * HDIM) / 4);

  WtArgs wa;
  for (int j = 0; j < 6; ++j) wa.W[j] = (const float*)d_in[4 + 2 * j];
  wt_cast<<<dim3(32, 32, 6), 256, 0, stream>>>(wa, wt);

  ProjArgs pa;
  const short* Xs[6] = {hbf, hbf, hbf, hbf, ebf, ebf};
  short* outs[6] = {qo, ko, vT, kqo, kko, kvT};
  const int Ms[6] = {4096, 4096, 4096, 4096, 2048, 2048};
  const int tsh[6] = {10, 10, 10, 10, 9, 9};
  const int md[6] = {0, 0, 1, 0, 0, 1};
  for (int j = 0; j < 6; ++j) {
    pa.X[j] = Xs[j];
    pa.Wt[j] = wt + (size_t)j * (HDIM * HDIM);
    pa.bias[j] = (const float*)d_in[5 + 2 * j];
    pa.out[j] = outs[j];
    pa.M[j] = Ms[j];
    pa.tshift[j] = tsh[j];
    pa.mode[j] = md[j];
  }
  proj_gemm<<<dim3(8, 32, 6), 256, 0, stream>>>(pa);

  attn_kernel<<<1024, 256, 0, stream>>>(qo, ko, vT, kqo, kko, kvT, amask, emask,
                                        (float*)d_out);
}

// Round 2
// 151.623 us; speedup vs baseline: 1.2580x; 1.2580x over previous
//
#include <hip/hip_runtime.h>

// ---- constants -------------------------------------------------------------
#define BATCH 4
#define SEQ   1024
#define KENC  512
#define HDIM  1024
#define NHEAD 16
#define HD    64
#define LOG2E 1.44269504088896340736f

typedef __attribute__((ext_vector_type(8))) short bf16x8;
typedef __attribute__((ext_vector_type(4))) float f32x4;
typedef __attribute__((ext_vector_type(4))) float f4v;
typedef __attribute__((ext_vector_type(4))) short s4v;

__device__ __forceinline__ short f2bf(float f) {
  unsigned u = __float_as_uint(f);
  u += 0x7fffu + ((u >> 16) & 1u);   // RNE
  return (short)(u >> 16);
}

__device__ __forceinline__ void gload_lds16(const void* g, void* l) {
  __builtin_amdgcn_global_load_lds(
      (const __attribute__((address_space(1))) void*)g,
      (__attribute__((address_space(3))) void*)l, 16, 0, 0);
}

// DPP-based 16-lane reductions (VALU pipe, frees DS pipe)
template <int C>
__device__ __forceinline__ float dppf(float x) {
  return __int_as_float(
      __builtin_amdgcn_update_dpp(0, __float_as_int(x), C, 0xF, 0xF, false));
}
__device__ __forceinline__ float red16_max(float x) {
  x = fmaxf(x, dppf<0xB1>(x));    // quad_perm [1,0,3,2]  (xor1)
  x = fmaxf(x, dppf<0x4E>(x));    // quad_perm [2,3,0,1]  (xor2)
  x = fmaxf(x, dppf<0x141>(x));   // row_half_mirror      (xor within 8)
  x = fmaxf(x, dppf<0x140>(x));   // row_mirror           (xor within 16)
  return x;
}
__device__ __forceinline__ float red16_sum(float x) {
  x += dppf<0xB1>(x);
  x += dppf<0x4E>(x);
  x += dppf<0x141>(x);
  x += dppf<0x140>(x);
  return x;
}

// ---- kernel 1: f32 -> bf16 cast (vectorized) -------------------------------
__global__ __launch_bounds__(256) void cast_bf16(const float* __restrict__ src,
                                                 short* __restrict__ dst, int n4) {
  int i = blockIdx.x * 256 + threadIdx.x;
  if (i >= n4) return;
  f4v v = ((const f4v*)src)[i];
  s4v o;
#pragma unroll
  for (int j = 0; j < 4; ++j) o[j] = f2bf(v[j]);
  ((s4v*)dst)[i] = o;
}

// ---- kernel 2: weight cast + transpose: Wt[n][k] = W[k][n] -----------------
struct WtArgs { const float* W[6]; };

__global__ __launch_bounds__(256) void wt_cast(WtArgs a, short* __restrict__ wt) {
  int j = blockIdx.z;
  const float* W = a.W[j];
  short* dst = wt + (size_t)j * (HDIM * HDIM);
  int cb = blockIdx.x * 32, rb = blockIdx.y * 32;
  __shared__ float t[32][33];
  int tx = threadIdx.x & 31, ty = threadIdx.x >> 5;
#pragma unroll
  for (int rr = 0; rr < 4; ++rr)
    t[ty + rr * 8][tx] = W[(size_t)(rb + ty + rr * 8) * HDIM + cb + tx];
  __syncthreads();
#pragma unroll
  for (int rr = 0; rr < 4; ++rr)
    dst[(size_t)(cb + ty + rr * 8) * HDIM + rb + tx] = f2bf(t[tx][ty + rr * 8]);
}

// ---- kernel 3: batched projection GEMM (128x128 tile, BK=32) ---------------
struct ProjArgs {
  const short* X[6];
  const short* Wt[6];
  const float* bias[6];
  short* out[6];
  int M[6];
  int tshift[6];  // log2(tokens): 10 or 9
  int mode[6];    // 0 std, 1 transposed
  float scale[6]; // epilogue scale (0.125*log2e for q/kq)
};

__global__ __launch_bounds__(256) void proj_gemm(ProjArgs a) {
  int job = blockIdx.z;
  int M = a.M[job];
  int by = blockIdx.y;
  if (by * 128 >= M) return;
  int bx = blockIdx.x;
  const short* X = a.X[job];
  const short* W = a.Wt[job];

  __shared__ short As[128 * 32];
  __shared__ short Bs[128 * 32];

  int tid = threadIdx.x, lane = tid & 63, wave = tid >> 6;
  int wr = wave >> 1, wc = wave & 1;
  int l15 = lane & 15, g4 = lane >> 4;

  f32x4 acc[4][4];
#pragma unroll
  for (int m = 0; m < 4; ++m)
#pragma unroll
    for (int n = 0; n < 4; ++n)
#pragma unroll
      for (int r = 0; r < 4; ++r) acc[m][n][r] = 0.0f;

  int arow = by * 128, brow = bx * 128;
  const int crow = lane >> 2;
  const int sgrp = (lane & 3) ^ ((lane >> 2) & 3) ^ (lane >> 4);
  const int rsw = (lane & 3) ^ ((l15) >> 2);

  for (int k0 = 0; k0 < HDIM; k0 += 32) {
#pragma unroll
    for (int cc = 0; cc < 2; ++cc) {
      int c = wave * 2 + cc;
      gload_lds16(X + (size_t)(arow + c * 16 + crow) * HDIM + k0 + sgrp * 8,
                  (char*)As + c * 1024);
      gload_lds16(W + (size_t)(brow + c * 16 + crow) * HDIM + k0 + sgrp * 8,
                  (char*)Bs + c * 1024);
    }
    __syncthreads();
    bf16x8 af[4], bfr[4];
#pragma unroll
    for (int m = 0; m < 4; ++m)
      af[m] = *(const bf16x8*)((const char*)As + (wr * 64 + m * 16 + l15) * 64 +
                               ((g4 ^ rsw) << 4));
#pragma unroll
    for (int n = 0; n < 4; ++n)
      bfr[n] = *(const bf16x8*)((const char*)Bs + (wc * 64 + n * 16 + l15) * 64 +
                                ((g4 ^ rsw) << 4));
#pragma unroll
    for (int m = 0; m < 4; ++m)
#pragma unroll
      for (int n = 0; n < 4; ++n)
        acc[m][n] = __builtin_amdgcn_mfma_f32_16x16x32_bf16(af[m], bfr[n],
                                                            acc[m][n], 0, 0, 0);
    __syncthreads();
  }

  const float* bias = a.bias[job];
  short* out = a.out[job];
  int tshift = a.tshift[job], tmask = (1 << tshift) - 1, mode = a.mode[job];
  float scl = a.scale[job];
#pragma unroll
  for (int m = 0; m < 4; ++m) {
    int rowb = arow + wr * 64 + m * 16 + (g4 << 2);
#pragma unroll
    for (int n = 0; n < 4; ++n) {
      int col = brow + wc * 64 + n * 16 + l15;
      float bv = bias[col];
      int head = col >> 6, d = col & 63;
#pragma unroll
      for (int r = 0; r < 4; ++r) {
        int row = rowb + r;
        int bb = row >> tshift, t = row & tmask;
        float val = (acc[m][n][r] + bv) * scl;
        size_t idx;
        if (mode == 0)
          idx = ((((size_t)bb * NHEAD + head) << tshift) + t) * 64 + d;
        else
          idx = ((((size_t)bb * NHEAD + head) * 64 + d) << tshift) + t;
        out[idx] = f2bf(val);
      }
    }
  }
}

// ---- kernel 4: fused dual-branch flash attention (2-phase pipeline) --------
__global__ __launch_bounds__(256, 3) void attn_kernel(
    const short* __restrict__ qall, const short* __restrict__ kall,
    const short* __restrict__ vTall, const short* __restrict__ kqall,
    const short* __restrict__ kkall, const short* __restrict__ kvTall,
    const float* __restrict__ amask, const float* __restrict__ emask,
    float* __restrict__ out) {
  __shared__ short Ks[2 * 64 * 64];
  __shared__ short Vs[2 * 64 * 64];
  __shared__ short Ps[4 * 16 * 64];

  int lid = blockIdx.x;
  int id = ((lid & 7) << 7) | (lid >> 3);   // XCD-chunked swizzle (1024 = 8*128)
  int bh = id >> 4, qb = id & 15;
  int b = bh >> 4, h = bh & 15;
  int lane = threadIdx.x & 63, wave = threadIdx.x >> 6;
  int l15 = lane & 15, g4 = lane >> 4, l7 = lane & 7;
  int srow = lane >> 3;
  int scol = (l7 ^ srow) * 8;               // pre-swizzled source 16B-group
  int qbase = qb * 64;
  char* Pw = (char*)(Ps + wave * 1024);

  // q fragments (q/kq already scaled by 0.125*log2e in proj)
  const short* qp  = qall  + ((size_t)bh * SEQ + qbase + wave * 16) * 64;
  const short* kqp = kqall + ((size_t)bh * SEQ + qbase + wave * 16) * 64;
  bf16x8 qf0  = *(const bf16x8*)(qp  + l15 * 64 + g4 * 8);
  bf16x8 qf1  = *(const bf16x8*)(qp  + l15 * 64 + 32 + g4 * 8);
  bf16x8 kqf0 = *(const bf16x8*)(kqp + l15 * 64 + g4 * 8);
  bf16x8 kqf1 = *(const bf16x8*)(kqp + l15 * 64 + 32 + g4 * 8);

  const short* kp0 = kall   + (size_t)bh * SEQ * 64;
  const short* vp0 = vTall  + (size_t)bh * 64 * SEQ;
  const short* kp1 = kkall  + (size_t)bh * KENC * 64;
  const short* vp1 = kvTall + (size_t)bh * 64 * KENC;

  bf16x8 qc0 = qf0, qc1 = qf1;
  const float* mpc = amask + (size_t)b * SEQ;

  auto STAGE = [&](int pb, const short* kptr, const short* vptr, int Tt, int kt) {
#pragma unroll
    for (int cc = 0; cc < 2; ++cc) {
      int c = wave * 2 + cc;
      int row = c * 8 + srow;
      gload_lds16(kptr + (size_t)(kt * 64 + row) * 64 + scol,
                  (char*)Ks + pb * 8192 + c * 1024);
      gload_lds16(vptr + (size_t)row * Tt + kt * 64 + scol,
                  (char*)Vs + pb * 8192 + c * 1024);
    }
  };

  STAGE(0, kp0, vp0, SEQ, 0);

  f32x4 ctx[4], c1[4], mr, lr;
#pragma unroll
  for (int i = 0; i < 4; ++i) {
#pragma unroll
    for (int r = 0; r < 4; ++r) { ctx[i][r] = 0.0f; c1[i][r] = 0.0f; }
    mr[i] = -1e30f;
    lr[i] = 0.0f;
  }

#pragma unroll 2
  for (int t = 0; t < 24; ++t) {
    int p = t & 1;
    __syncthreads();                        // drains vmcnt: tile-t loads landed
    if (t < 23) {                           // prefetch tile t+1 (flies under compute)
      int tn = t + 1;
      bool nb = tn >= 16;
      const short* skp = nb ? kp1 : kp0;
      const short* svp = nb ? vp1 : vp0;
      int sT = nb ? KENC : SEQ;
      int skt = nb ? tn - 16 : tn;
      STAGE(p ^ 1, skp, svp, sT, skt);
    }
    if (t == 16) {                          // finalize self branch, switch to enc
#pragma unroll
      for (int dt = 0; dt < 4; ++dt) {
#pragma unroll
        for (int r = 0; r < 4; ++r) {
          c1[dt][r] = ctx[dt][r] * __builtin_amdgcn_rcpf(lr[r]);
          ctx[dt][r] = 0.0f;
        }
      }
#pragma unroll
      for (int r = 0; r < 4; ++r) { mr[r] = -1e30f; lr[r] = 0.0f; }
      qc0 = kqf0;
      qc1 = kqf1;
      mpc = emask + (size_t)b * KENC;
    }
    int kt = (t >= 16) ? t - 16 : t;
    const char* Kb = (const char*)Ks + p * 8192;
    const char* Vb = (const char*)Vs + p * 8192;

    float mk[4];
#pragma unroll
    for (int t2 = 0; t2 < 4; ++t2) mk[t2] = mpc[kt * 64 + t2 * 16 + l15] * LOG2E;

    f32x4 sc[4];
#pragma unroll
    for (int t2 = 0; t2 < 4; ++t2)
#pragma unroll
      for (int r = 0; r < 4; ++r) sc[t2][r] = 0.0f;

    __builtin_amdgcn_s_setprio(1);
#pragma unroll
    for (int t2 = 0; t2 < 4; ++t2) {
      bf16x8 kf0 = *(const bf16x8*)(Kb + (t2 * 16 + l15) * 128 + ((g4 ^ l7) << 4));
      bf16x8 kf1 = *(const bf16x8*)(Kb + (t2 * 16 + l15) * 128 + (((4 + g4) ^ l7) << 4));
      sc[t2] = __builtin_amdgcn_mfma_f32_16x16x32_bf16(qc0, kf0, sc[t2], 0, 0, 0);
      sc[t2] = __builtin_amdgcn_mfma_f32_16x16x32_bf16(qc1, kf1, sc[t2], 0, 0, 0);
    }
    __builtin_amdgcn_s_setprio(0);

#pragma unroll
    for (int t2 = 0; t2 < 4; ++t2)
#pragma unroll
      for (int r = 0; r < 4; ++r) sc[t2][r] += mk[t2];

    // online softmax in log2 domain; DPP reductions
    f32x4 rm;
#pragma unroll
    for (int r = 0; r < 4; ++r)
      rm[r] = fmaxf(fmaxf(sc[0][r], sc[1][r]), fmaxf(sc[2][r], sc[3][r]));
#pragma unroll
    for (int r = 0; r < 4; ++r) rm[r] = red16_max(rm[r]);

    int need = (rm[0] > mr[0] + 12.f) || (rm[1] > mr[1] + 12.f) ||
               (rm[2] > mr[2] + 12.f) || (rm[3] > mr[3] + 12.f);
    if (__any(need)) {
#pragma unroll
      for (int r = 0; r < 4; ++r) {
        float mn = fmaxf(mr[r], rm[r]);
        float s = __builtin_amdgcn_exp2f(mr[r] - mn);
        mr[r] = mn;
        lr[r] *= s;
        ctx[0][r] *= s; ctx[1][r] *= s; ctx[2][r] *= s; ctx[3][r] *= s;
      }
    }

    f32x4 pv[4], rs;
#pragma unroll
    for (int r = 0; r < 4; ++r) rs[r] = 0.0f;
#pragma unroll
    for (int t2 = 0; t2 < 4; ++t2)
#pragma unroll
      for (int r = 0; r < 4; ++r) {
        pv[t2][r] = __builtin_amdgcn_exp2f(sc[t2][r] - mr[r]);
        rs[r] += pv[t2][r];
      }
#pragma unroll
    for (int r = 0; r < 4; ++r) lr[r] += red16_sum(rs[r]);

    // P -> per-wave LDS (swizzled), then A-fragment reads
#pragma unroll
    for (int t2 = 0; t2 < 4; ++t2) {
      int gg = t2 * 2 + (l15 >> 3);
#pragma unroll
      for (int r4 = 0; r4 < 4; ++r4) {
        int rr = g4 * 4 + r4;
        *(short*)(Pw + rr * 128 + (((gg ^ (rr & 7)) << 4) | (l7 * 2))) =
            f2bf(pv[t2][r4]);
      }
    }
    __builtin_amdgcn_s_setprio(1);
#pragma unroll
    for (int kc = 0; kc < 2; ++kc) {
      bf16x8 pf = *(const bf16x8*)(Pw + l15 * 128 + (((kc * 4 + g4) ^ l7) << 4));
#pragma unroll
      for (int dt = 0; dt < 4; ++dt) {
        bf16x8 vf = *(const bf16x8*)(Vb + (dt * 16 + l15) * 128 +
                                     (((kc * 4 + g4) ^ l7) << 4));
        ctx[dt] = __builtin_amdgcn_mfma_f32_16x16x32_bf16(pf, vf, ctx[dt], 0, 0, 0);
      }
    }
    __builtin_amdgcn_s_setprio(0);
  }

#pragma unroll
  for (int dt = 0; dt < 4; ++dt)
#pragma unroll
    for (int r = 0; r < 4; ++r) {
      float v2 = ctx[dt][r] * __builtin_amdgcn_rcpf(lr[r]);
      int s = qbase + wave * 16 + g4 * 4 + r;
      int d = dt * 16 + l15;
      out[((size_t)b * SEQ + s) * HDIM + h * 64 + d] = 0.5f * (c1[dt][r] + v2);
    }
}

// ---- host launcher ---------------------------------------------------------
extern "C" void kernel_launch(void* const* d_in, const int* in_sizes, int n_in,
                              void* d_out, int out_size, void* d_ws, size_t ws_size,
                              hipStream_t stream) {
  const float* hid = (const float*)d_in[0];
  const float* enc = (const float*)d_in[1];
  const float* amask = (const float*)d_in[2];
  const float* emask = (const float*)d_in[3];

  char* ws = (char*)d_ws;
  short* hbf = (short*)(ws);                        // 8 MB  [B*S,H] bf16
  short* ebf = (short*)(ws + (8u << 20));           // 4 MB  [B*K,H]
  short* wt = (short*)(ws + (12u << 20));           // 12 MB 6x [n][k]
  short* qo = (short*)(ws + (24u << 20));           // 8 MB  [B,NH,S,HD]
  short* ko = (short*)(ws + (32u << 20));           // 8 MB
  short* vT = (short*)(ws + (40u << 20));           // 8 MB  [B,NH,HD,S]
  short* kqo = (short*)(ws + (48u << 20));          // 8 MB
  short* kko = (short*)(ws + (56u << 20));          // 4 MB  [B,NH,K,HD]
  short* kvT = (short*)(ws + (60u << 20));          // 4 MB  [B,NH,HD,K]

  cast_bf16<<<4096, 256, 0, stream>>>(hid, hbf, (BATCH * SEQ * HDIM) / 4);
  cast_bf16<<<2048, 256, 0, stream>>>(enc, ebf, (BATCH * KENC * HDIM) / 4);

  WtArgs wa;
  for (int j = 0; j < 6; ++j) wa.W[j] = (const float*)d_in[4 + 2 * j];
  wt_cast<<<dim3(32, 32, 6), 256, 0, stream>>>(wa, wt);

  ProjArgs pa;
  const short* Xs[6] = {hbf, hbf, hbf, hbf, ebf, ebf};
  short* outs[6] = {qo, ko, vT, kqo, kko, kvT};
  const int Ms[6] = {4096, 4096, 4096, 4096, 2048, 2048};
  const int tsh[6] = {10, 10, 10, 10, 9, 9};
  const int md[6] = {0, 0, 1, 0, 0, 1};
  const float qscale = 0.125f * LOG2E;
  const float scl[6] = {qscale, 1.f, 1.f, qscale, 1.f, 1.f};
  for (int j = 0; j < 6; ++j) {
    pa.X[j] = Xs[j];
    pa.Wt[j] = wt + (size_t)j * (HDIM * HDIM);
    pa.bias[j] = (const float*)d_in[5 + 2 * j];
    pa.out[j] = outs[j];
    pa.M[j] = Ms[j];
    pa.tshift[j] = tsh[j];
    pa.mode[j] = md[j];
    pa.scale[j] = scl[j];
  }
  proj_gemm<<<dim3(8, 32, 6), 256, 0, stream>>>(pa);

  attn_kernel<<<1024, 256, 0, stream>>>(qo, ko, vT, kqo, kko, kvT, amask, emask,
                                        (float*)d_out);
}